// Round 1
// baseline (3249.683 us; speedup 1.0000x reference)
//
#include <hip/hip_runtime.h>
#include <hip/hip_fp16.h>

// Problem constants
#define B_   64
#define T_   512
#define I_   128
#define H_   256
#define G4_  1024   // 4*H
#define R_   20
#define DA_  50
#define C_   10

typedef _Float16 half2_t __attribute__((ext_vector_type(2)));

#if __has_builtin(__builtin_amdgcn_fdot2)
#define USE_FDOT2 1
#endif

// ---------------------------------------------------------------------------
// K0: pack W_hh [256][1024] fp32 -> [128][1024] half2 (adjacent k pairs)
// ---------------------------------------------------------------------------
__global__ __launch_bounds__(256) void k0_pack(const float* __restrict__ Whh,
                                               half2_t* __restrict__ Wp) {
  int idx = blockIdx.x * 256 + threadIdx.x;   // 0..131071 = k2*1024 + g
  int k2 = idx >> 10, g = idx & 1023;
  half2_t h;
  h.x = (_Float16)Whh[(2 * k2) * G4_ + g];
  h.y = (_Float16)Whh[(2 * k2 + 1) * G4_ + g];
  Wp[idx] = h;
}

// ---------------------------------------------------------------------------
// K1: S[b][r][t] = (tanh(x[b,t,:]@W1[r,:]+b1)@W2[r,:]) + b2   (layout [B,R,T])
// one wave per (b,t)
// ---------------------------------------------------------------------------
__global__ __launch_bounds__(64) void k1_scores(const float* __restrict__ x,
                                                const float* __restrict__ W1,
                                                const float* __restrict__ b1,
                                                const float* __restrict__ W2,
                                                const float* __restrict__ b2,
                                                float* __restrict__ S) {
  int bt = blockIdx.x;            // b*512 + t
  int b = bt >> 9, t = bt & 511;
  int l = threadIdx.x;
  __shared__ float xs[I_];
  __shared__ float as[DA_];
  const float* xr = x + (size_t)bt * I_;
  xs[l] = xr[l];
  xs[l + 64] = xr[l + 64];
  __syncthreads();
  if (l < DA_) {
    float acc = b1[l];
    const float* wr = W1 + l * I_;
#pragma unroll 8
    for (int k = 0; k < I_; k++) acc += xs[k] * wr[k];
    as[l] = tanhf(acc);
  }
  __syncthreads();
  if (l < R_) {
    float acc = b2[l];
    const float* wr = W2 + l * DA_;
#pragma unroll 5
    for (int d = 0; d < DA_; d++) acc += as[d] * wr[d];
    S[((size_t)(b * R_ + l)) * T_ + t] = acc;
  }
}

// ---------------------------------------------------------------------------
// K2: per (b,r): m = max_t S; E = exp(S-m); invd[t] = 1/cumsum(E)[t]
// one wave per (b,r), layout [B,R,T] contiguous in t
// ---------------------------------------------------------------------------
__global__ __launch_bounds__(64) void k2_prefix(const float* __restrict__ S,
                                                float* __restrict__ E,
                                                float* __restrict__ invd) {
  int br = blockIdx.x;            // b*20 + r
  int l = threadIdx.x;
  const float* Sr = S + (size_t)br * T_;
  float v[8];
  float m = -1e30f;
#pragma unroll
  for (int c = 0; c < 8; c++) {
    v[c] = Sr[c * 64 + l];
    m = fmaxf(m, v[c]);
  }
#pragma unroll
  for (int off = 32; off; off >>= 1) m = fmaxf(m, __shfl_xor(m, off));
  float carry = 0.f;
  for (int c = 0; c < 8; c++) {
    float e = expf(v[c] - m);
    float s = e;
#pragma unroll
    for (int off = 1; off < 64; off <<= 1) {
      float u = __shfl_up(s, off);
      if (l >= off) s += u;
    }
    E[(size_t)br * T_ + c * 64 + l] = e;
    invd[(size_t)br * T_ + c * 64 + l] = 1.f / (carry + s);
    carry += __shfl(s, 63);
  }
}

// ---------------------------------------------------------------------------
// K3: M[b,t,i] = (1/R) * sum_r (sum_{s<=t} E[b,s,r] x[b,s,i]) * invd[b,t,r]
// one block (128 threads, thread=i) per b; sequential t with acc[r] registers
// ---------------------------------------------------------------------------
__global__ __launch_bounds__(128) void k3_context(const float* __restrict__ x,
                                                  const float* __restrict__ E,
                                                  const float* __restrict__ invd,
                                                  float* __restrict__ M) {
  int b = blockIdx.x;
  int i = threadIdx.x;
  __shared__ float es[2][R_], ds[2][R_];
  float acc[R_];
#pragma unroll
  for (int r = 0; r < R_; r++) acc[r] = 0.f;
  float rE = 0.f, rD = 0.f;
  if (i < R_)
    rE = E[((size_t)(b * R_ + i)) * T_ + 0];
  else if (i < 2 * R_)
    rD = invd[((size_t)(b * R_ + (i - R_))) * T_ + 0];
  const float* xb = x + (size_t)b * T_ * I_;
  float xv = xb[i];
  int buf = 0;
  for (int t = 0; t < T_; t++) {
    if (i < R_) es[buf][i] = rE;
    else if (i < 2 * R_) ds[buf][i - R_] = rD;
    __syncthreads();
    if (t + 1 < T_) {
      if (i < R_)
        rE = E[((size_t)(b * R_ + i)) * T_ + t + 1];
      else if (i < 2 * R_)
        rD = invd[((size_t)(b * R_ + (i - R_))) * T_ + t + 1];
    }
    float xcur = xv;
    if (t + 1 < T_) xv = xb[(size_t)(t + 1) * I_ + i];
    float s = 0.f;
#pragma unroll
    for (int r = 0; r < R_; r++) {
      acc[r] += es[buf][r] * xcur;
      s += acc[r] * ds[buf][r];
    }
    M[(size_t)b * T_ * I_ + (size_t)t * I_ + i] = s * (1.0f / R_);
    buf ^= 1;
  }
}

// ---------------------------------------------------------------------------
// K4: gx[row][g] = M[row,:] @ W_ih[:,g] + b[g], row = b*512+t.  Output fp16.
// 64x64 tile per 256-thread block, K=128 in one shot, 4x4 register tile.
// ---------------------------------------------------------------------------
__global__ __launch_bounds__(256) void k4_gemm(const float* __restrict__ Mm,
                                               const float* __restrict__ Wih,
                                               const float* __restrict__ bg,
                                               __half* __restrict__ gx) {
  __shared__ float As[I_][64];   // [k][row] 32KB
  __shared__ float Bs[I_][64];   // [k][col] 32KB
  int row0 = blockIdx.x * 64, col0 = blockIdx.y * 64;
  int tid = threadIdx.x;
  // load A tile (transpose into [k][row])
#pragma unroll
  for (int ch = 0; ch < 8; ch++) {
    int fidx = ch * 256 + tid;       // 0..2047 float4s
    int r = fidx >> 5;               // 32 float4 per row
    int kk = (fidx & 31) << 2;
    float4 f = ((const float4*)(Mm + (size_t)(row0 + r) * I_))[fidx & 31];
    As[kk + 0][r] = f.x;
    As[kk + 1][r] = f.y;
    As[kk + 2][r] = f.z;
    As[kk + 3][r] = f.w;
  }
  // load B tile
#pragma unroll
  for (int ch = 0; ch < 8; ch++) {
    int fidx = ch * 256 + tid;       // 0..2047 float4s
    int k = fidx >> 4;               // 16 float4 per row
    int c4 = (fidx & 15) << 2;
    float4 f = *((const float4*)(Wih + (size_t)k * G4_ + col0 + c4));
    *((float4*)&Bs[k][c4]) = f;
  }
  __syncthreads();
  int ty = tid >> 4, tx = tid & 15;
  float acc[4][4] = {};
#pragma unroll 4
  for (int k = 0; k < I_; k++) {
    float4 a = *((float4*)&As[k][ty << 2]);
    float4 bq = *((float4*)&Bs[k][tx << 2]);
    acc[0][0] += a.x * bq.x; acc[0][1] += a.x * bq.y; acc[0][2] += a.x * bq.z; acc[0][3] += a.x * bq.w;
    acc[1][0] += a.y * bq.x; acc[1][1] += a.y * bq.y; acc[1][2] += a.y * bq.z; acc[1][3] += a.y * bq.w;
    acc[2][0] += a.z * bq.x; acc[2][1] += a.z * bq.y; acc[2][2] += a.z * bq.z; acc[2][3] += a.z * bq.w;
    acc[3][0] += a.w * bq.x; acc[3][1] += a.w * bq.y; acc[3][2] += a.w * bq.z; acc[3][3] += a.w * bq.w;
  }
#pragma unroll
  for (int ii = 0; ii < 4; ii++) {
#pragma unroll
    for (int jj = 0; jj < 4; jj++) {
      int row = row0 + (ty << 2) + ii;
      int col = col0 + (tx << 2) + jj;
      gx[(size_t)row * G4_ + col] = __float2half(acc[ii][jj] + bg[col]);
    }
  }
}

// ---------------------------------------------------------------------------
// K5: LSTM scan. One block (1024 threads) per b; thread = gate column.
// W_hh streamed from L2 as packed fp16 pairs; h broadcast from LDS.
// ---------------------------------------------------------------------------
__global__ __launch_bounds__(1024) void k5_lstm(const __half* __restrict__ gx,
                                                const half2_t* __restrict__ Wp,
                                                float* __restrict__ hT) {
  int b = blockIdx.x;
  int g = threadIdx.x;
  __shared__ half2_t h2s[H_ / 2];
  __shared__ float gs[G4_];
  float c = 1.0f;                 // c0 = 1, owned by threads g<256
  if (g < H_ / 2) {
    half2_t o;
    o.x = (_Float16)1.0f;
    o.y = (_Float16)1.0f;
    h2s[g] = o;                   // h0 = 1
  }
  __syncthreads();
  const __half* gxb = gx + (size_t)b * T_ * G4_;
  for (int t = 0; t < T_; t++) {
    float s = (float)gxb[(size_t)t * G4_ + g];   // bias already folded in
#pragma unroll 8
    for (int k2 = 0; k2 < H_ / 2; k2++) {
      half2_t w = Wp[(k2 << 10) + g];
      half2_t h2 = h2s[k2];
#ifdef USE_FDOT2
      s = __builtin_amdgcn_fdot2(w, h2, s, false);
#else
      s += (float)w.x * (float)h2.x + (float)w.y * (float)h2.y;
#endif
    }
    gs[g] = s;
    __syncthreads();
    if (g < H_) {
      float vi = gs[g], vf = gs[g + H_], vg = gs[g + 2 * H_], vo = gs[g + 3 * H_];
      vi = 1.f / (1.f + expf(-vi));
      vf = 1.f / (1.f + expf(-vf));
      vo = 1.f / (1.f + expf(-vo));
      vg = tanhf(vg);
      c = vf * c + vi * vg;
      float h = vo * tanhf(c);
      ((__half*)h2s)[g] = __float2half(h);
      if (t == T_ - 1) hT[b * H_ + g] = h;
    }
    __syncthreads();
  }
}

// ---------------------------------------------------------------------------
// K6: logits = hT @ Wfc^T + bfc; softmax.  One wave per b.
// ---------------------------------------------------------------------------
__global__ __launch_bounds__(64) void k6_head(const float* __restrict__ hT,
                                              const float* __restrict__ Wfc,
                                              const float* __restrict__ bfc,
                                              float* __restrict__ out) {
  int b = blockIdx.x, l = threadIdx.x;
  const float* h = hT + b * H_;
  float p[C_];
#pragma unroll
  for (int c = 0; c < C_; c++) p[c] = 0.f;
#pragma unroll
  for (int q = 0; q < 4; q++) {
    float hv = h[q * 64 + l];
#pragma unroll
    for (int c = 0; c < C_; c++) p[c] += hv * Wfc[c * H_ + q * 64 + l];
  }
#pragma unroll
  for (int c = 0; c < C_; c++)
    for (int off = 32; off; off >>= 1) p[c] += __shfl_xor(p[c], off);
  if (l == 0) {
    float m = -1e30f, e[C_], sum = 0.f;
    for (int c = 0; c < C_; c++) { p[c] += bfc[c]; m = fmaxf(m, p[c]); }
    for (int c = 0; c < C_; c++) { e[c] = expf(p[c] - m); sum += e[c]; }
    for (int c = 0; c < C_; c++) out[b * C_ + c] = e[c] / sum;
  }
}

// ---------------------------------------------------------------------------
// Workspace layout (float offsets):
//   S     [B,R,T]        655360 f
//   E     [B,R,T]        655360 f
//   INVD  [B,R,T]        655360 f
//   M     [B,T,I]        4194304 f
//   hT    [B,H]          16384 f
//   Wp    [128][1024]h2  131072 dwords
//   gx    [B,T,4H] fp16  16777216 dwords
// total ~92.3 MB — requires ws_size >= 93MB
// ---------------------------------------------------------------------------
extern "C" void kernel_launch(void* const* d_in, const int* in_sizes, int n_in,
                              void* d_out, int out_size, void* d_ws, size_t ws_size,
                              hipStream_t stream) {
  const float* x   = (const float*)d_in[0];
  const float* Wih = (const float*)d_in[1];
  const float* Whh = (const float*)d_in[2];
  const float* bg  = (const float*)d_in[3];
  const float* W1  = (const float*)d_in[4];
  const float* b1  = (const float*)d_in[5];
  const float* W2  = (const float*)d_in[6];
  const float* b2  = (const float*)d_in[7];
  const float* Wfc = (const float*)d_in[8];
  const float* bfc = (const float*)d_in[9];
  float* out = (float*)d_out;

  float* wsf = (float*)d_ws;
  float* S    = wsf;
  float* E    = wsf + 655360;
  float* INVD = wsf + 1310720;
  float* Mm   = wsf + 1966080;
  float* hT   = wsf + 6160384;
  half2_t* Wp = (half2_t*)(wsf + 6176768);
  __half* gx  = (__half*)(wsf + 6307840);

  hipLaunchKernelGGL(k0_pack,   dim3(512),      dim3(256), 0, stream, Whh, Wp);
  hipLaunchKernelGGL(k1_scores, dim3(B_ * T_),  dim3(64),  0, stream, x, W1, b1, W2, b2, S);
  hipLaunchKernelGGL(k2_prefix, dim3(B_ * R_),  dim3(64),  0, stream, S, E, INVD);
  hipLaunchKernelGGL(k3_context,dim3(B_),       dim3(128), 0, stream, x, E, INVD, Mm);
  hipLaunchKernelGGL(k4_gemm,   dim3(512, 16),  dim3(256), 0, stream, Mm, Wih, bg, gx);
  hipLaunchKernelGGL(k5_lstm,   dim3(B_),       dim3(1024),0, stream, gx, Wp, hT);
  hipLaunchKernelGGL(k6_head,   dim3(B_),       dim3(64),  0, stream, hT, Wfc, bfc, out);
}